// Round 17
// baseline (61.141 us; speedup 1.0000x reference)
//
#include <hip/hip_runtime.h>

// KiloNeRF fused MLP — 32x32x16 MFMA, layer-folded, WIDE-REG 2-tile ILP.
// R17 theory: previous 2-tile ILP failed (sum-not-max) because tight reg
// budgets (launch_bounds .,4 => ~128 regs) forced the compiler to finish
// tile A before starting tile B. Fix: __launch_bounds__(256,2) (~256 regs,
// 2 waves/SIMD) + explicit A/B interleave + split-C MFMA pairs (two
// independent MFMAs + VALU add instead of a serial C-chain).
//   prep:  Wc[k][m] = sum_t wf[k][t]*wv[t][m];  bvEff = bv + bf·Wv_feat
//   per tile chain: bx -> L0(+b0) -> L1(+b1, split) -> fold(h1·Wc+cv, split)
//                   -> rgb(split, rows 0..2) ; sigma via fdot2 off-chain
// br/bs at store; cross-iteration x prefetch.

#define NPTS   4194304
#define NT32   (NPTS / 32)

typedef _Float16 f16;
typedef _Float16 f16x2 __attribute__((ext_vector_type(2)));
typedef _Float16 f16x8 __attribute__((ext_vector_type(8)));
typedef __fp16   h16x2 __attribute__((ext_vector_type(2)));
typedef float    f32x16 __attribute__((ext_vector_type(16)));

union H8 { f16x8 v; unsigned u[4]; };

static __device__ __forceinline__ unsigned pkrtz(float a, float b) {
    return __builtin_bit_cast(unsigned, __builtin_amdgcn_cvt_pkrtz(a, b));
}
static __device__ __forceinline__ unsigned relu2(unsigned w) {
    f16x2 h = __builtin_bit_cast(f16x2, w);
    f16x2 z = (f16x2)(f16)0.f;
    return __builtin_bit_cast(unsigned, __builtin_elementwise_max(h, z));
}
static __device__ __forceinline__ float fdot2(unsigned a, unsigned b, float c) {
    return __builtin_amdgcn_fdot2(__builtin_bit_cast(h16x2, a),
                                  __builtin_bit_cast(h16x2, b), c, false);
}

#define MFMA32(A, B, C) __builtin_amdgcn_mfma_f32_32x32x16_f16((A), (B), (C), 0, 0, 0)

// ---- prep: compose Wc (1024 f32) and bvEff (32 f32) into workspace ----
__global__ __launch_bounds__(1024) void kilonerf_prep(
    const float* __restrict__ wf, const float* __restrict__ bf,
    const float* __restrict__ wv, const float* __restrict__ bv,
    float* __restrict__ ws_out)
{
    const int tid = threadIdx.x;
    const int k = tid >> 5, m = tid & 31;
    float acc = 0.f;
#pragma unroll 8
    for (int t = 0; t < 32; ++t)
        acc = fmaf(wf[k * 32 + t], wv[t * 32 + m], acc);
    ws_out[k * 32 + m] = acc;          // Wc
    if (tid < 32) {
        float b = bv[tid];
#pragma unroll 8
        for (int t = 0; t < 32; ++t)
            b = fmaf(bf[t], wv[t * 32 + tid], b);
        ws_out[1024 + tid] = b;        // bvEff
    }
}

__global__ __launch_bounds__(256, 2) void kilonerf_r17(
    const float* __restrict__ x,
    const float* __restrict__ w0, const float* __restrict__ b0,
    const float* __restrict__ w1, const float* __restrict__ b1,
    const float* __restrict__ ws, const float* __restrict__ bs,
    const float* __restrict__ wv, const float* __restrict__ wr,
    const float* __restrict__ br,
    const float* __restrict__ wsp,   // workspace: Wc[1024], bvEff[32]
    float* __restrict__ out)
{
    const int lane = threadIdx.x & 63;
    const int m  = lane & 31;
    const int hi = lane >> 5;

    int sj[8], row[16];
#pragma unroll
    for (int j = 0; j < 8; ++j)  sj[j]  = (j & 3) + 8 * (j >> 2) + 4 * hi;
#pragma unroll
    for (int r = 0; r < 16; ++r) row[r] = (r & 3) + 8 * (r >> 2) + 4 * hi;

    const float* Wc    = wsp;
    const float* bvEff = wsp + 1024;

    f16x8 aw0x, awv2x, aw1lo, aw1hi, awclo, awchi, awrlo, awrhi;
#pragma unroll
    for (int j = 0; j < 8; ++j) {
        const int k = sj[j];
        aw0x[j]  = (k < 3) ? (f16)w0[k * 32 + m]
                  : (k == 3 ? (f16)b0[m] : (f16)0.f);
        awv2x[j] = (k >= 4 && k < 7) ? (f16)wv[(32 + (k - 4)) * 32 + m]
                  : (k == 7 ? (f16)bvEff[m] : (f16)0.f);
        aw1lo[j] = (f16)w1[k * 32 + m];
        aw1hi[j] = (f16)w1[(16 + k) * 32 + m];
        awclo[j] = (f16)Wc[k * 32 + m];
        awchi[j] = (f16)Wc[(16 + k) * 32 + m];
        awrlo[j] = (m < 3) ? (f16)wr[k * 3 + m] : (f16)0.f;
        awrhi[j] = (m < 3) ? (f16)wr[(16 + k) * 3 + m] : (f16)0.f;
    }

    unsigned wspk[8];
#pragma unroll
    for (int w = 0; w < 8; ++w)
        wspk[w] = pkrtz(ws[row[2 * w]], ws[row[2 * w + 1]]);

    f32x16 b1c;
#pragma unroll
    for (int r = 0; r < 16; ++r) b1c[r] = b1[row[r]];

    const float br0 = br[0], br1 = br[1], br2 = br[2], bs0 = bs[0];

    f32x16 zf;
#pragma unroll
    for (int r = 0; r < 16; ++r) zf[r] = 0.f;

    const int wslot  = blockIdx.x * 4 + (threadIdx.x >> 6);
    const int nslots = gridDim.x * 4;      // 8192 waves
    const int npairs = NT32 / 2;           // 65536 pairs of 32-pt tiles

    // ---- prefetch first pair's x ----
    float2 ax0, ax1, ax2, bx0, bx1, bx2;
    {
        const float2* pa = reinterpret_cast<const float2*>(
            x + (size_t)(wslot * 64 + m) * 6);
        const float2* pb = reinterpret_cast<const float2*>(
            x + (size_t)(wslot * 64 + 32 + m) * 6);
        ax0 = pa[0]; ax1 = pa[1]; ax2 = pa[2];
        bx0 = pb[0]; bx1 = pb[1]; bx2 = pb[2];
    }

    for (int pair = wslot; pair < npairs; pair += nslots) {
        int np = pair + nslots; if (np >= npairs) np = wslot;
        const float2* pa = reinterpret_cast<const float2*>(
            x + (size_t)(np * 64 + m) * 6);
        const float2* pb = reinterpret_cast<const float2*>(
            x + (size_t)(np * 64 + 32 + m) * 6);
        float2 nax0 = pa[0], nax1 = pa[1], nax2 = pa[2];
        float2 nbx0 = pb[0], nbx1 = pb[1], nbx2 = pb[2];

        // merged input fragments
        H8 bxA, bxB;
        {
            const float fa = hi ? ax1.y : ax0.x;
            const float fb = hi ? ax2.x : ax0.y;
            const float fc = hi ? ax2.y : ax1.x;
            bxA.u[0] = pkrtz(fa, fb); bxA.u[1] = pkrtz(fc, 1.0f);
            bxA.u[2] = 0u; bxA.u[3] = 0u;
        }
        {
            const float fa = hi ? bx1.y : bx0.x;
            const float fb = hi ? bx2.x : bx0.y;
            const float fc = hi ? bx2.y : bx1.x;
            bxB.u[0] = pkrtz(fa, fb); bxB.u[1] = pkrtz(fc, 1.0f);
            bxB.u[2] = 0u; bxB.u[3] = 0u;
        }

        // ---- L0 + view-partial for both tiles (4 independent MFMAs) ----
        f32x16 c0A = MFMA32(aw0x,  bxA.v, zf);
        f32x16 c0B = MFMA32(aw0x,  bxB.v, zf);
        f32x16 cvA = MFMA32(awv2x, bxA.v, zf);
        f32x16 cvB = MFMA32(awv2x, bxB.v, zf);

        H8 loA, hiA, loB, hiB;
        loA.u[0] = relu2(pkrtz(c0A[0], c0A[1]));
        loA.u[1] = relu2(pkrtz(c0A[2], c0A[3]));
        loA.u[2] = relu2(pkrtz(c0A[4], c0A[5]));
        loA.u[3] = relu2(pkrtz(c0A[6], c0A[7]));
        hiA.u[0] = relu2(pkrtz(c0A[8], c0A[9]));
        hiA.u[1] = relu2(pkrtz(c0A[10], c0A[11]));
        hiA.u[2] = relu2(pkrtz(c0A[12], c0A[13]));
        hiA.u[3] = relu2(pkrtz(c0A[14], c0A[15]));
        loB.u[0] = relu2(pkrtz(c0B[0], c0B[1]));
        loB.u[1] = relu2(pkrtz(c0B[2], c0B[3]));
        loB.u[2] = relu2(pkrtz(c0B[4], c0B[5]));
        loB.u[3] = relu2(pkrtz(c0B[6], c0B[7]));
        hiB.u[0] = relu2(pkrtz(c0B[8], c0B[9]));
        hiB.u[1] = relu2(pkrtz(c0B[10], c0B[11]));
        hiB.u[2] = relu2(pkrtz(c0B[12], c0B[13]));
        hiB.u[3] = relu2(pkrtz(c0B[14], c0B[15]));

        // ---- L1 split-C: 4 independent MFMAs, then VALU merge ----
        f32x16 p0A = MFMA32(aw1lo, loA.v, b1c);
        f32x16 p1A = MFMA32(aw1hi, hiA.v, zf);
        f32x16 p0B = MFMA32(aw1lo, loB.v, b1c);
        f32x16 p1B = MFMA32(aw1hi, hiB.v, zf);
        f32x16 c1A = p0A + p1A;
        f32x16 c1B = p0B + p1B;

        loA.u[0] = relu2(pkrtz(c1A[0], c1A[1]));
        loA.u[1] = relu2(pkrtz(c1A[2], c1A[3]));
        loA.u[2] = relu2(pkrtz(c1A[4], c1A[5]));
        loA.u[3] = relu2(pkrtz(c1A[6], c1A[7]));
        hiA.u[0] = relu2(pkrtz(c1A[8], c1A[9]));
        hiA.u[1] = relu2(pkrtz(c1A[10], c1A[11]));
        hiA.u[2] = relu2(pkrtz(c1A[12], c1A[13]));
        hiA.u[3] = relu2(pkrtz(c1A[14], c1A[15]));
        loB.u[0] = relu2(pkrtz(c1B[0], c1B[1]));
        loB.u[1] = relu2(pkrtz(c1B[2], c1B[3]));
        loB.u[2] = relu2(pkrtz(c1B[4], c1B[5]));
        loB.u[3] = relu2(pkrtz(c1B[6], c1B[7]));
        hiB.u[0] = relu2(pkrtz(c1B[8], c1B[9]));
        hiB.u[1] = relu2(pkrtz(c1B[10], c1B[11]));
        hiB.u[2] = relu2(pkrtz(c1B[12], c1B[13]));
        hiB.u[3] = relu2(pkrtz(c1B[14], c1B[15]));

        // sigma (off-chain, VALU)
        float sA0 = 0.f, sA1 = 0.f, sB0 = 0.f, sB1 = 0.f;
#pragma unroll
        for (int w = 0; w < 4; ++w) {
            sA0 = fdot2(loA.u[w], wspk[w], sA0);
            sA1 = fdot2(hiA.u[w], wspk[4 + w], sA1);
            sB0 = fdot2(loB.u[w], wspk[w], sB0);
            sB1 = fdot2(hiB.u[w], wspk[4 + w], sB1);
        }
        float sgA = sA0 + sA1; sgA += __shfl_xor(sgA, 32);
        float sgB = sB0 + sB1; sgB += __shfl_xor(sgB, 32);

        // ---- folded layer split-C: h1·Wc + cv ----
        f32x16 q0A = MFMA32(awclo, loA.v, cvA);
        f32x16 q1A = MFMA32(awchi, hiA.v, zf);
        f32x16 q0B = MFMA32(awclo, loB.v, cvB);
        f32x16 q1B = MFMA32(awchi, hiB.v, zf);
        f32x16 ccA = q0A + q1A;
        f32x16 ccB = q0B + q1B;

        loA.u[0] = relu2(pkrtz(ccA[0], ccA[1]));
        loA.u[1] = relu2(pkrtz(ccA[2], ccA[3]));
        loA.u[2] = relu2(pkrtz(ccA[4], ccA[5]));
        loA.u[3] = relu2(pkrtz(ccA[6], ccA[7]));
        hiA.u[0] = relu2(pkrtz(ccA[8], ccA[9]));
        hiA.u[1] = relu2(pkrtz(ccA[10], ccA[11]));
        hiA.u[2] = relu2(pkrtz(ccA[12], ccA[13]));
        hiA.u[3] = relu2(pkrtz(ccA[14], ccA[15]));
        loB.u[0] = relu2(pkrtz(ccB[0], ccB[1]));
        loB.u[1] = relu2(pkrtz(ccB[2], ccB[3]));
        loB.u[2] = relu2(pkrtz(ccB[4], ccB[5]));
        loB.u[3] = relu2(pkrtz(ccB[6], ccB[7]));
        hiB.u[0] = relu2(pkrtz(ccB[8], ccB[9]));
        hiB.u[1] = relu2(pkrtz(ccB[10], ccB[11]));
        hiB.u[2] = relu2(pkrtz(ccB[12], ccB[13]));
        hiB.u[3] = relu2(pkrtz(ccB[14], ccB[15]));

        // ---- rgb split-C (only rows 0..2 needed) ----
        f32x16 r0A = MFMA32(awrlo, loA.v, zf);
        f32x16 r1A = MFMA32(awrhi, hiA.v, zf);
        f32x16 r0B = MFMA32(awrlo, loB.v, zf);
        f32x16 r1B = MFMA32(awrhi, hiB.v, zf);

        if (hi == 0) {
            float4 oA = make_float4(r0A[0] + r1A[0] + br0,
                                    r0A[1] + r1A[1] + br1,
                                    r0A[2] + r1A[2] + br2, sgA + bs0);
            float4 oB = make_float4(r0B[0] + r1B[0] + br0,
                                    r0B[1] + r1B[1] + br1,
                                    r0B[2] + r1B[2] + br2, sgB + bs0);
            *reinterpret_cast<float4*>(out + (size_t)(pair * 64 + m) * 4) = oA;
            *reinterpret_cast<float4*>(out + (size_t)(pair * 64 + 32 + m) * 4) = oB;
        }

        ax0 = nax0; ax1 = nax1; ax2 = nax2;
        bx0 = nbx0; bx1 = nbx1; bx2 = nbx2;
    }
}

extern "C" void kernel_launch(void* const* d_in, const int* in_sizes, int n_in,
                              void* d_out, int out_size, void* d_ws, size_t ws_size,
                              hipStream_t stream) {
    const float* x  = (const float*)d_in[0];
    const float* w0 = (const float*)d_in[1];
    const float* b0 = (const float*)d_in[2];
    const float* w1 = (const float*)d_in[3];
    const float* b1 = (const float*)d_in[4];
    const float* wf = (const float*)d_in[5];
    const float* bf = (const float*)d_in[6];
    const float* ws = (const float*)d_in[7];
    const float* bs = (const float*)d_in[8];
    const float* wv = (const float*)d_in[9];
    const float* bv = (const float*)d_in[10];
    const float* wr = (const float*)d_in[11];
    const float* br = (const float*)d_in[12];
    float* out = (float*)d_out;
    float* wsp = (float*)d_ws;

    kilonerf_prep<<<dim3(1), dim3(1024), 0, stream>>>(wf, bf, wv, bv, wsp);

    dim3 block(256);
    dim3 grid(2048);
    kilonerf_r17<<<grid, block, 0, stream>>>(x, w0, b0, w1, b1,
                                             ws, bs, wv, wr, br, wsp, out);
}

// Round 18
// 55.251 us; speedup vs baseline: 1.1066x; 1.1066x over previous
//
#include <hip/hip_runtime.h>

// KiloNeRF fused MLP — 32x32x16 MFMA, layer-folded, single-kernel version.
// R18 = R15 (best: 57.5 us) with the prep kernel DELETED:
//  - Wc = WF·WVf composed in-wave via 2 MFMA32s in setup. Fragment algebra:
//    A[m][sj[j]] = wf[m*32+sj[j]], B[sj[j]][m] = wv[sj[j]*32+m] gives
//    D[reg r] = Wc[row[r]][m], and row[j]==sj[j], row[8+j]==16+sj[j], so
//    awclo[j]=(f16)D[j], awchi[j]=(f16)D[8+j] directly.
//  - bvEff = bv + bf·Wv_feat via a one-time 32-FMA per-lane loop (coalesced).
// Removes one dispatch + graph gap from the timed path; zero workspace.
//   main chain per 32-pt tile (6 MFMAs):
//   bx -> L0(+b0) -> L1(+b1) -> fold(h1·Wc + cv) -> rgb ; sigma via fdot2;
//   cv (views+bvEff) computed late off the critical path; br/bs at store;
//   cross-iteration x prefetch.

#define NPTS   4194304
#define NT32   (NPTS / 32)

typedef _Float16 f16;
typedef _Float16 f16x2 __attribute__((ext_vector_type(2)));
typedef _Float16 f16x8 __attribute__((ext_vector_type(8)));
typedef __fp16   h16x2 __attribute__((ext_vector_type(2)));
typedef float    f32x16 __attribute__((ext_vector_type(16)));

union H8 { f16x8 v; unsigned u[4]; };

static __device__ __forceinline__ unsigned pkrtz(float a, float b) {
    return __builtin_bit_cast(unsigned, __builtin_amdgcn_cvt_pkrtz(a, b));
}
static __device__ __forceinline__ unsigned relu2(unsigned w) {
    f16x2 h = __builtin_bit_cast(f16x2, w);
    f16x2 z = (f16x2)(f16)0.f;
    return __builtin_bit_cast(unsigned, __builtin_elementwise_max(h, z));
}
static __device__ __forceinline__ float fdot2(unsigned a, unsigned b, float c) {
    return __builtin_amdgcn_fdot2(__builtin_bit_cast(h16x2, a),
                                  __builtin_bit_cast(h16x2, b), c, false);
}

#define MFMA32(A, B, C) __builtin_amdgcn_mfma_f32_32x32x16_f16((A), (B), (C), 0, 0, 0)

__global__ __launch_bounds__(256, 4) void kilonerf_r18(
    const float* __restrict__ x,
    const float* __restrict__ w0, const float* __restrict__ b0,
    const float* __restrict__ w1, const float* __restrict__ b1,
    const float* __restrict__ wf, const float* __restrict__ bf,
    const float* __restrict__ ws, const float* __restrict__ bs,
    const float* __restrict__ wv, const float* __restrict__ bv,
    const float* __restrict__ wr, const float* __restrict__ br,
    float* __restrict__ out)
{
    const int lane = threadIdx.x & 63;
    const int m  = lane & 31;     // output channel (A row) / point (B,C col)
    const int hi = lane >> 5;     // lane half

    int sj[8], row[16];
#pragma unroll
    for (int j = 0; j < 8; ++j)  sj[j]  = (j & 3) + 8 * (j >> 2) + 4 * hi;
#pragma unroll
    for (int r = 0; r < 16; ++r) row[r] = (r & 3) + 8 * (r >> 2) + 4 * hi;

    f32x16 zf;
#pragma unroll
    for (int r = 0; r < 16; ++r) zf[r] = 0.f;

    // ---- one-time: bvEff[m] = bv[m] + sum_t bf[t]*wv[t*32+m] ----
    float bve = bv[m];
#pragma unroll 8
    for (int t = 0; t < 32; ++t) bve = fmaf(wv[t * 32 + m], bf[t], bve);

    // ---- one-time: Wc = WF·WVf via 2 MFMA32s ----
    f16x8 afw1, afw2, bwv1, bwv2;
#pragma unroll
    for (int j = 0; j < 8; ++j) {
        const int k = sj[j];
        afw1[j] = (f16)wf[m * 32 + k];
        afw2[j] = (f16)wf[m * 32 + 16 + k];
        bwv1[j] = (f16)wv[k * 32 + m];
        bwv2[j] = (f16)wv[(16 + k) * 32 + m];
    }
    f32x16 dwc = MFMA32(afw1, bwv1, zf);
    dwc = MFMA32(afw2, bwv2, dwc);
    f16x8 awclo, awchi;
#pragma unroll
    for (int j = 0; j < 8; ++j) {
        awclo[j] = (f16)dwc[j];
        awchi[j] = (f16)dwc[8 + j];
    }

    // ---- one-time weight fragment gathers (all cached loads) ----
    f16x8 aw0x, awv2x, aw1lo, aw1hi;
#pragma unroll
    for (int j = 0; j < 8; ++j) {
        const int k = sj[j];
        aw0x[j]  = (k < 3) ? (f16)w0[k * 32 + m]
                  : (k == 3 ? (f16)b0[m] : (f16)0.f);
        awv2x[j] = (k >= 4 && k < 7) ? (f16)wv[(32 + (k - 4)) * 32 + m]
                  : (k == 7 ? (f16)bve : (f16)0.f);
        aw1lo[j] = (f16)w1[k * 32 + m];
        aw1hi[j] = (f16)w1[(16 + k) * 32 + m];
    }

    // sigma weights packed f16: word w pairs channels (row[2w], row[2w+1])
    unsigned wspk[8];
#pragma unroll
    for (int w = 0; w < 8; ++w)
        wspk[w] = pkrtz(ws[row[2 * w]], ws[row[2 * w + 1]]);

    // rgb weights (A-fragment form, rows 0..2 of the 32-row output)
    f16x8 awrlo, awrhi;
#pragma unroll
    for (int j = 0; j < 8; ++j) {
        const int k = sj[j];
        awrlo[j] = (m < 3) ? (f16)wr[k * 3 + m] : (f16)0.f;
        awrhi[j] = (m < 3) ? (f16)wr[(16 + k) * 3 + m] : (f16)0.f;
    }

    // L1 bias C-init
    f32x16 b1c;
#pragma unroll
    for (int r = 0; r < 16; ++r) b1c[r] = b1[row[r]];

    const float br0 = br[0], br1 = br[1], br2 = br[2], bs0 = bs[0];

    const int wslot  = blockIdx.x * 4 + (threadIdx.x >> 6);
    const int nslots = gridDim.x * 4;   // 8192 waves

    // ---- prefetch first tile's x ----
    float2 cx0, cx1, cx2;
    {
        const float2* xp2 = reinterpret_cast<const float2*>(
            x + (size_t)(wslot * 32 + m) * 6);
        cx0 = xp2[0]; cx1 = xp2[1]; cx2 = xp2[2];
    }

    for (int tile = wslot; tile < NT32; tile += nslots) {
        // issue next tile's loads early (wraps to a valid address at end)
        int np = tile + nslots; if (np >= NT32) np = wslot;
        const float2* xn = reinterpret_cast<const float2*>(
            x + (size_t)(np * 32 + m) * 6);
        float2 nx0 = xn[0], nx1 = xn[1], nx2 = xn[2];

        // merged input fragment: hi=0 -> {p0,p1,p2,1} at k=0..3,
        //                        hi=1 -> {v0,v1,v2,1} at k=4..7
        const float fa = hi ? cx1.y : cx0.x;
        const float fb = hi ? cx2.x : cx0.y;
        const float fc = hi ? cx2.y : cx1.x;
        H8 bx;
        bx.u[0] = pkrtz(fa, fb);
        bx.u[1] = pkrtz(fc, 1.0f);
        bx.u[2] = 0u;
        bx.u[3] = 0u;

        // ---- layer 0: 3 -> 32 (+b0 via k=3), relu ----
        f32x16 c0 = MFMA32(aw0x, bx.v, zf);

        H8 blo, bhi;
        blo.u[0] = relu2(pkrtz(c0[0], c0[1]));
        blo.u[1] = relu2(pkrtz(c0[2], c0[3]));
        blo.u[2] = relu2(pkrtz(c0[4], c0[5]));
        blo.u[3] = relu2(pkrtz(c0[6], c0[7]));
        bhi.u[0] = relu2(pkrtz(c0[8], c0[9]));
        bhi.u[1] = relu2(pkrtz(c0[10], c0[11]));
        bhi.u[2] = relu2(pkrtz(c0[12], c0[13]));
        bhi.u[3] = relu2(pkrtz(c0[14], c0[15]));

        // ---- layer 1: 32 -> 32 (+b1 via C-init), relu ----
        f32x16 c1 = MFMA32(aw1lo, blo.v, b1c);
        c1 = MFMA32(aw1hi, bhi.v, c1);

        blo.u[0] = relu2(pkrtz(c1[0], c1[1]));
        blo.u[1] = relu2(pkrtz(c1[2], c1[3]));
        blo.u[2] = relu2(pkrtz(c1[4], c1[5]));
        blo.u[3] = relu2(pkrtz(c1[6], c1[7]));
        bhi.u[0] = relu2(pkrtz(c1[8], c1[9]));
        bhi.u[1] = relu2(pkrtz(c1[10], c1[11]));
        bhi.u[2] = relu2(pkrtz(c1[12], c1[13]));
        bhi.u[3] = relu2(pkrtz(c1[14], c1[15]));

        // sigma = ws . relu(h1) via packed dot2 (f32 accumulate)
        float s0 = 0.f, s1 = 0.f;
#pragma unroll
        for (int w = 0; w < 4; ++w) {
            s0 = fdot2(blo.u[w], wspk[w], s0);
            s1 = fdot2(bhi.u[w], wspk[4 + w], s1);
        }
        float sg = s0 + s1;
        sg += __shfl_xor(sg, 32);

        // ---- view partial (late): views(3)+bvEff from still-live bx ----
        f32x16 cv = MFMA32(awv2x, bx.v, zf);

        // ---- folded feature+view layer: h1·Wc + cv (in-place), relu ----
        cv = MFMA32(awclo, blo.v, cv);
        cv = MFMA32(awchi, bhi.v, cv);

        blo.u[0] = relu2(pkrtz(cv[0], cv[1]));
        blo.u[1] = relu2(pkrtz(cv[2], cv[3]));
        blo.u[2] = relu2(pkrtz(cv[4], cv[5]));
        blo.u[3] = relu2(pkrtz(cv[6], cv[7]));
        bhi.u[0] = relu2(pkrtz(cv[8], cv[9]));
        bhi.u[1] = relu2(pkrtz(cv[10], cv[11]));
        bhi.u[2] = relu2(pkrtz(cv[12], cv[13]));
        bhi.u[3] = relu2(pkrtz(cv[14], cv[15]));

        // ---- rgb: 32 -> 3 (rows 0..2 valid; +br at store) ----
        f32x16 cr = MFMA32(awrlo, blo.v, zf);
        cr = MFMA32(awrhi, bhi.v, cr);

        // ---- store: hi==0 lanes hold rgb rows 0..2 for their point ----
        if (hi == 0) {
            float4 o = make_float4(cr[0] + br0, cr[1] + br1,
                                   cr[2] + br2, sg + bs0);
            *reinterpret_cast<float4*>(out + (size_t)(tile * 32 + m) * 4) = o;
        }

        cx0 = nx0; cx1 = nx1; cx2 = nx2;
    }
}

extern "C" void kernel_launch(void* const* d_in, const int* in_sizes, int n_in,
                              void* d_out, int out_size, void* d_ws, size_t ws_size,
                              hipStream_t stream) {
    const float* x  = (const float*)d_in[0];
    const float* w0 = (const float*)d_in[1];
    const float* b0 = (const float*)d_in[2];
    const float* w1 = (const float*)d_in[3];
    const float* b1 = (const float*)d_in[4];
    const float* wf = (const float*)d_in[5];
    const float* bf = (const float*)d_in[6];
    const float* ws = (const float*)d_in[7];
    const float* bs = (const float*)d_in[8];
    const float* wv = (const float*)d_in[9];
    const float* bv = (const float*)d_in[10];
    const float* wr = (const float*)d_in[11];
    const float* br = (const float*)d_in[12];
    float* out = (float*)d_out;

    dim3 block(256);
    dim3 grid(2048);
    kilonerf_r18<<<grid, block, 0, stream>>>(x, w0, b0, w1, b1, wf, bf,
                                             ws, bs, wv, bv, wr, br, out);
}